// Round 1
// baseline (1320.186 us; speedup 1.0000x reference)
//
#include <hip/hip_runtime.h>
#include <math.h>

// LoE tiled MLP, fully fused, fp32 VALU version.
//
// Geometry: 512x512 pixel grid. Block = 256 threads = 32 pixels (8 rows x 4 cols
// of pixels). Pixel slot p in [0,32): p = s*4 + q where s in [0,8) is a 2x2
// spatial sub-block (sr=s>>1 row, sc=s&1 col), q in [0,4) position inside it.
// All 4 pixels of a sub-block share idx0/idx1/idx2 -> per-thread-uniform weights.
//
// Thread t: tp = t>>5 in [0,8) owns sub-block tp (4 pixels); tn = t&31 owns an
// 8-wide slice of the 256 output columns. Register tile: 4 px x 8 cols = 32 acc.
//
// LDS: two 32x256 fp32 activation buffers (ping-pong), posenc (32x56) overlaid
// on the buffer that is written only later. Total 64 KiB -> 2 blocks/CU.

#define DH 256

__device__ __forceinline__ void pix_ij(int p, int& di, int& dj) {
    di = ((p >> 3) << 1) | ((p >> 1) & 1);   // sr*2 + (q>>1)
    dj = (((p >> 2) & 1) << 1) | (p & 1);    // sc*2 + (q&1)
}

__device__ __forceinline__ float leaky(float v) {
    return v > 0.f ? v : 0.2f * v;
}

// One FC layer: [32 x K] (LDS, stride hin_stride) @ [K x 256] + b -> leakyrelu
// -> [32 x 256] (LDS, stride 256). K templated so tails fold at compile time.
template<int K>
__device__ __forceinline__
void layer(const float* __restrict__ w,   // already offset to the tile: [K][256]
           const float* __restrict__ b,   // [256]
           const float* hin, float* hout,
           int hin_stride, int tp, int tn)
{
    float acc[4][8];
#pragma unroll
    for (int r = 0; r < 4; ++r)
#pragma unroll
        for (int c = 0; c < 8; ++c) acc[r][c] = 0.f;

    const float* wt = w + tn * 8;
    const float* hp = hin + (tp * 4) * hin_stride;

#pragma unroll 2
    for (int k4 = 0; k4 < K / 4; ++k4) {
        float4 hv[4];
#pragma unroll
        for (int r = 0; r < 4; ++r)
            hv[r] = *(const float4*)(hp + r * hin_stride + k4 * 4);
#pragma unroll
        for (int kk = 0; kk < 4; ++kk) {
            float4 wa = *(const float4*)(wt + (k4 * 4 + kk) * DH);
            float4 wb = *(const float4*)(wt + (k4 * 4 + kk) * DH + 4);
#pragma unroll
            for (int r = 0; r < 4; ++r) {
                float hvr = ((const float*)&hv[r])[kk];
                acc[r][0] = fmaf(hvr, wa.x, acc[r][0]);
                acc[r][1] = fmaf(hvr, wa.y, acc[r][1]);
                acc[r][2] = fmaf(hvr, wa.z, acc[r][2]);
                acc[r][3] = fmaf(hvr, wa.w, acc[r][3]);
                acc[r][4] = fmaf(hvr, wb.x, acc[r][4]);
                acc[r][5] = fmaf(hvr, wb.y, acc[r][5]);
                acc[r][6] = fmaf(hvr, wb.z, acc[r][6]);
                acc[r][7] = fmaf(hvr, wb.w, acc[r][7]);
            }
        }
    }
    // K % 4 tail (layer 0: K=54 -> k=52,53)
#pragma unroll
    for (int k = (K / 4) * 4; k < K; ++k) {
        float4 wa = *(const float4*)(wt + k * DH);
        float4 wb = *(const float4*)(wt + k * DH + 4);
#pragma unroll
        for (int r = 0; r < 4; ++r) {
            float hvr = hp[r * hin_stride + k];
            acc[r][0] = fmaf(hvr, wa.x, acc[r][0]);
            acc[r][1] = fmaf(hvr, wa.y, acc[r][1]);
            acc[r][2] = fmaf(hvr, wa.z, acc[r][2]);
            acc[r][3] = fmaf(hvr, wa.w, acc[r][3]);
            acc[r][4] = fmaf(hvr, wb.x, acc[r][4]);
            acc[r][5] = fmaf(hvr, wb.y, acc[r][5]);
            acc[r][6] = fmaf(hvr, wb.z, acc[r][6]);
            acc[r][7] = fmaf(hvr, wb.w, acc[r][7]);
        }
    }

    float4 bv0 = *(const float4*)(b + tn * 8);
    float4 bv1 = *(const float4*)(b + tn * 8 + 4);
#pragma unroll
    for (int r = 0; r < 4; ++r) {
        float4 o0, o1;
        o0.x = leaky(acc[r][0] + bv0.x);
        o0.y = leaky(acc[r][1] + bv0.y);
        o0.z = leaky(acc[r][2] + bv0.z);
        o0.w = leaky(acc[r][3] + bv0.w);
        o1.x = leaky(acc[r][4] + bv1.x);
        o1.y = leaky(acc[r][5] + bv1.y);
        o1.z = leaky(acc[r][6] + bv1.z);
        o1.w = leaky(acc[r][7] + bv1.w);
        float* op = hout + (tp * 4 + r) * DH + tn * 8;
        *(float4*)op = o0;
        *(float4*)(op + 4) = o1;
    }
}

__global__ __launch_bounds__(256, 2)
void loe_fused(const float* __restrict__ w0, const float* __restrict__ b0,
               const float* __restrict__ w1, const float* __restrict__ b1,
               const float* __restrict__ w2, const float* __restrict__ b2,
               const float* __restrict__ wl, const float* __restrict__ bl,
               float* __restrict__ out)
{
    __shared__ float hA[32 * DH];   // 32 KiB
    __shared__ float hB[32 * DH];   // 32 KiB; posenc h0 (32x56) overlaid here

    const int t  = threadIdx.x;
    const int tp = t >> 5;
    const int tn = t & 31;
    const int i0 = blockIdx.y * 8;
    const int j0 = blockIdx.x * 4;

    // ---------- positional encoding -> hB as [32][56] ----------
    {
        const int p    = t >> 3;   // pixel 0..31
        const int part = t & 7;    // 8 threads per pixel
        int di, dj; pix_ij(p, di, dj);
        const float xi = (float)(i0 + di) * (1.f / 256.f) - 1.f;
        const float xj = (float)(j0 + dj) * (1.f / 256.f) - 1.f;
        float* h0 = hB + p * 56;
#pragma unroll
        for (int f = part; f < 13; f += 8) {
            // freq = pi * 2^f : exact exponent scaling of fp32 pi, matches jnp
            const float fr = 3.14159265358979323846f * (float)(1 << f);
            float si, ci, sj, cj;
            sincosf(xi * fr, &si, &ci);
            sincosf(xj * fr, &sj, &cj);
            h0[2 + f * 4 + 0] = si;
            h0[2 + f * 4 + 1] = ci;
            h0[2 + f * 4 + 2] = sj;
            h0[2 + f * 4 + 3] = cj;
        }
        if (part == 5) h0[0] = xi;
        if (part == 6) h0[1] = xj;
    }
    __syncthreads();

    // ---------- tile indices (exact integer forms of the reference) ----------
    const int idx0 = (((i0 >> 5) & 3) << 2) | ((j0 >> 5) & 3);
    const int idx1 = (((i0 >> 3) & 3) << 2) | ((j0 >> 3) & 3);
    const int i_sub = i0 + (tp >> 1) * 2;
    const int j_sub = j0 + (tp & 1) * 2;
    const int idx2 = (((i_sub >> 1) & 3) << 2) | ((j_sub >> 1) & 3);

    // ---------- layer 0: hB(posenc, stride 56) -> hA ----------
    layer<54>(w0 + idx0 * (54 * DH), b0, hB, hA, 56, tp, tn);
    __syncthreads();

    // ---------- layer 1: hA -> hB ----------
    layer<256>(w1 + idx1 * (DH * DH), b1, hA, hB, DH, tp, tn);
    __syncthreads();

    // ---------- layer 2: hB -> hA ----------
    layer<256>(w2 + idx2 * (DH * DH), b2, hB, hA, DH, tp, tn);
    __syncthreads();

    // ---------- head: [32 x 256] @ [256 x 3] + b_last -> out ----------
    if (t < 96) {
        const int p = t / 3;
        const int c = t - p * 3;
        const float* hrow = hA + p * DH;
        float accf = 0.f;
#pragma unroll 4
        for (int k4 = 0; k4 < DH / 4; ++k4) {
            float4 hv = *(const float4*)(hrow + k4 * 4);
            accf = fmaf(hv.x, wl[(k4 * 4 + 0) * 3 + c], accf);
            accf = fmaf(hv.y, wl[(k4 * 4 + 1) * 3 + c], accf);
            accf = fmaf(hv.z, wl[(k4 * 4 + 2) * 3 + c], accf);
            accf = fmaf(hv.w, wl[(k4 * 4 + 3) * 3 + c], accf);
        }
        int di, dj; pix_ij(p, di, dj);
        const int i = i0 + di, j = j0 + dj;
        out[(i * 512 + j) * 3 + c] = accf + bl[c];
    }
}

extern "C" void kernel_launch(void* const* d_in, const int* in_sizes, int n_in,
                              void* d_out, int out_size, void* d_ws, size_t ws_size,
                              hipStream_t stream) {
    // inputs: x, labels, w0, b0, w1, b1, w2, b2, w_last, b_last
    const float* w0 = (const float*)d_in[2];
    const float* b0 = (const float*)d_in[3];
    const float* w1 = (const float*)d_in[4];
    const float* b1 = (const float*)d_in[5];
    const float* w2 = (const float*)d_in[6];
    const float* b2 = (const float*)d_in[7];
    const float* wl = (const float*)d_in[8];
    const float* bl = (const float*)d_in[9];
    float* out = (float*)d_out;

    dim3 grid(512 / 4, 512 / 8);   // j-blocks x i-blocks = 128 x 64
    loe_fused<<<grid, 256, 0, stream>>>(w0, b0, w1, b1, w2, b2, wl, bl, out);
}

// Round 2
// 323.462 us; speedup vs baseline: 4.0814x; 4.0814x over previous
//
#include <hip/hip_runtime.h>
#include <math.h>

// LoE tiled MLP — bf16 MFMA version.
//
// Block = 16x16 pixel region (256 px), 512 threads = 8 waves.
// Tile indices (exact integer forms): idx0=((i>>5)&3)*4+((j>>5)&3) block-uniform;
// idx1=((i>>3)&3)*4+((j>>3)&3) -> 4 groups of 64 px; idx2=((i>>1)&3)*4+((j>>1)&3)
// -> 16 groups of 16 px (one MFMA M-tile each). Activations live in one 128 KiB
// bf16 LDS buffer; each layer accumulates ALL its outputs in registers
// (128 VGPR/thread), barriers, then rewrites the buffer permuted into the order
// the NEXT layer's grouping wants. Slot orderings (bits of di=d3d2d1d0,
// dj=e3e2e1e0):
//   ord1 = [d3 e3 | d2 d1 e2 e1 | d0 e0]  (L1 groups = s>>6, contiguous 64)
//   ord2 = [d2 d1 e2 e1 | d3 e3 | d0 e0]  (L2 groups = s>>4, contiguous 16 = idx2)
// Weights are pre-packed (pack_w) to bf16 in exact MFMA B-fragment order:
// [tile][kt][nt][lane][8], so B-loads are coalesced global_load_dwordx4.
// LDS XOR-swizzle byte^=((row&7)<<4) on all activation accesses (G4 fix).

typedef __attribute__((ext_vector_type(8))) short bf16x8;
typedef __attribute__((ext_vector_type(4))) float f32x4;

__device__ __forceinline__ unsigned short f2bf(float f){
    unsigned b = __float_as_uint(f);
    return (unsigned short)((b + 0x7FFFu + ((b >> 16) & 1u)) >> 16);
}
__device__ __forceinline__ float bf2f(unsigned short u){
    return __uint_as_float(((unsigned)u) << 16);
}
__device__ __forceinline__ int swz(int row, int bytecol, int stride){
    return row * stride + (bytecol ^ ((row & 7) << 4));
}
__device__ __forceinline__ float leaky(float v){ return v > 0.f ? v : 0.2f * v; }

// ---------------- weight pack: fp32 -> bf16 MFMA-B-fragment layout ----------
// ws layout (unsigned short units): w0p [16][2][16][64][8]  @ 0        (262144)
//                                   w1p [16][8][16][64][8]  @ 262144   (1048576)
//                                   w2p [16][8][16][64][8]  @ 1310720  (1048576)
__global__ void pack_w(const float* __restrict__ w0, const float* __restrict__ w1,
                       const float* __restrict__ w2, unsigned short* __restrict__ wp)
{
    int tid = blockIdx.x * 256 + threadIdx.x;
    if (tid < 32768) {
        int lane = tid & 63, nt = (tid >> 6) & 15, kt = (tid >> 10) & 1, tile = tid >> 11;
        int n = nt * 16 + (lane & 15);
        unsigned short* d = wp + tid * 8;
#pragma unroll
        for (int r = 0; r < 8; ++r) {
            int k = kt * 32 + (lane >> 4) * 8 + r;
            float v = (k < 54) ? w0[(tile * 54 + k) * 256 + n] : 0.f;
            d[r] = f2bf(v);
        }
    } else if (tid < 32768 + 131072) {
        int idx = tid - 32768;
        int lane = idx & 63, nt = (idx >> 6) & 15, kt = (idx >> 10) & 7, tile = idx >> 13;
        int n = nt * 16 + (lane & 15);
        unsigned short* d = wp + 262144 + idx * 8;
#pragma unroll
        for (int r = 0; r < 8; ++r) {
            int k = kt * 32 + (lane >> 4) * 8 + r;
            d[r] = f2bf(w1[(tile * 256 + k) * 256 + n]);
        }
    } else {
        int idx = tid - 163840;
        int lane = idx & 63, nt = (idx >> 6) & 15, kt = (idx >> 10) & 7, tile = idx >> 13;
        int n = nt * 16 + (lane & 15);
        unsigned short* d = wp + 1310720 + idx * 8;
#pragma unroll
        for (int r = 0; r < 8; ++r) {
            int k = kt * 32 + (lane >> 4) * 8 + r;
            d[r] = f2bf(w2[(tile * 256 + k) * 256 + n]);
        }
    }
}

// ---------------- per-wave GEMM: 4 Mtiles x 8 Ntiles, K = KT*32 -------------
template<int KT>
__device__ __forceinline__
void gemm48(const unsigned short* __restrict__ wp, int ntbase, int mtbase,
            const char* hin, int stride, int l15, int l4, int lane, f32x4 (&acc)[4][8])
{
#pragma unroll
    for (int kt = 0; kt < KT; ++kt) {
        bf16x8 a[4];
#pragma unroll
        for (int mt = 0; mt < 4; ++mt) {
            int row = (mtbase + mt) * 16 + l15;
            a[mt] = *(const bf16x8*)(hin + swz(row, kt * 64 + l4 * 16, stride));
        }
#pragma unroll
        for (int nt = 0; nt < 8; ++nt) {
            bf16x8 b = *(const bf16x8*)(wp + (((kt * 16) + ntbase + nt) * 64 + lane) * 8);
#pragma unroll
            for (int mt = 0; mt < 4; ++mt)
                acc[mt][nt] = __builtin_amdgcn_mfma_f32_16x16x32_bf16(a[mt], b, acc[mt][nt], 0, 0, 0);
        }
    }
}

__device__ __forceinline__
void write48(f32x4 (&acc)[4][8], char* hout, int mtbase, int ntbase,
             const float* __restrict__ bias, bool perm12, int l15, int l4)
{
#pragma unroll
    for (int nt = 0; nt < 8; ++nt) {
        int col = (ntbase + nt) * 16 + l15;
        float bv = bias[col];
#pragma unroll
        for (int mt = 0; mt < 4; ++mt) {
#pragma unroll
            for (int r = 0; r < 4; ++r) {
                float v = leaky(acc[mt][nt][r] + bv);
                int srow = (mtbase + mt) * 16 + l4 * 4 + r;
                int drow = perm12 ? (((srow & 0x3C) << 2) | ((srow >> 4) & 0xC) | (srow & 3)) : srow;
                *(unsigned short*)(hout + swz(drow, col * 2, 512)) = f2bf(v);
            }
        }
    }
}

__global__ __launch_bounds__(512, 2)
void loe_mfma(const unsigned short* __restrict__ wpk,
              const float* __restrict__ b0, const float* __restrict__ b1,
              const float* __restrict__ b2, const float* __restrict__ wl,
              const float* __restrict__ bl, float* __restrict__ out)
{
    __shared__ unsigned short hbuf[65536];   // 128 KiB
    char* hb = (char*)hbuf;

    const int t = threadIdx.x;
    const int wv = t >> 6, lane = t & 63;
    const int l15 = lane & 15, l4 = lane >> 4;
    const int bx = blockIdx.x, by = blockIdx.y;     // 32 x 32 blocks of 16x16 px

    const unsigned short* w0p = wpk;
    const unsigned short* w1p = wpk + 262144;
    const unsigned short* w2p = wpk + 1310720;

    // ---------- posenc -> h0 region [256 rows(ord1)][64 bf16], stride 128B ----
    {
        int s = t >> 1, half = t & 1;
        int d3 = (s >> 7) & 1, e3 = (s >> 6) & 1, d2 = (s >> 5) & 1, d1 = (s >> 4) & 1;
        int e2 = (s >> 3) & 1, e1 = (s >> 2) & 1, d0 = (s >> 1) & 1, e0 = s & 1;
        int di = d3 * 8 + d2 * 4 + d1 * 2 + d0, dj = e3 * 8 + e2 * 4 + e1 * 2 + e0;
        float xi = (float)(by * 16 + di) * (1.f / 256.f) - 1.f;
        float xj = (float)(bx * 16 + dj) * (1.f / 256.f) - 1.f;
        if (half == 0) {
            *(unsigned short*)(hb + swz(s, 0, 128)) = f2bf(xi);
            *(unsigned short*)(hb + swz(s, 2, 128)) = f2bf(xj);
#pragma unroll
            for (int f = 0; f < 7; ++f) {
                float fr = 3.14159265358979323846f * (float)(1 << f);
                float si, ci, sj, cj;
                sincosf(xi * fr, &si, &ci); sincosf(xj * fr, &sj, &cj);
                *(unsigned short*)(hb + swz(s, (2 + f * 4 + 0) * 2, 128)) = f2bf(si);
                *(unsigned short*)(hb + swz(s, (2 + f * 4 + 1) * 2, 128)) = f2bf(ci);
                *(unsigned short*)(hb + swz(s, (2 + f * 4 + 2) * 2, 128)) = f2bf(sj);
                *(unsigned short*)(hb + swz(s, (2 + f * 4 + 3) * 2, 128)) = f2bf(cj);
            }
        } else {
#pragma unroll
            for (int f = 7; f < 13; ++f) {
                float fr = 3.14159265358979323846f * (float)(1 << f);
                float si, ci, sj, cj;
                sincosf(xi * fr, &si, &ci); sincosf(xj * fr, &sj, &cj);
                *(unsigned short*)(hb + swz(s, (2 + f * 4 + 0) * 2, 128)) = f2bf(si);
                *(unsigned short*)(hb + swz(s, (2 + f * 4 + 1) * 2, 128)) = f2bf(ci);
                *(unsigned short*)(hb + swz(s, (2 + f * 4 + 2) * 2, 128)) = f2bf(sj);
                *(unsigned short*)(hb + swz(s, (2 + f * 4 + 3) * 2, 128)) = f2bf(cj);
            }
#pragma unroll
            for (int c = 54; c < 64; ++c)   // zero-pad K 54->64
                *(unsigned short*)(hb + swz(s, c * 2, 128)) = 0;
        }
    }
    __syncthreads();

    // ---------- layer 0: h0 (ord1, K=64 padded) -> hbuf (ord1) ---------------
    {
        const int tile0 = ((by >> 1) & 3) * 4 + ((bx >> 1) & 3);
        const int mtbase = (wv >> 1) * 4, ntbase = (wv & 1) * 8;
        f32x4 acc[4][8];
#pragma unroll
        for (int m = 0; m < 4; ++m)
#pragma unroll
            for (int n = 0; n < 8; ++n) acc[m][n] = (f32x4)0.f;
        gemm48<2>(w0p + tile0 * 16384, ntbase, mtbase, hb, 128, l15, l4, lane, acc);
        __syncthreads();
        write48(acc, hb, mtbase, ntbase, b0, false, l15, l4);
    }
    __syncthreads();

    // ---------- layer 1: hbuf (ord1) -> hbuf (ord2) --------------------------
    {
        const int g1 = wv >> 1;                       // (d3,e3)
        const int tile1 = ((by * 2 + (g1 >> 1)) & 3) * 4 + ((bx * 2 + (g1 & 1)) & 3);
        const int mtbase = g1 * 4, ntbase = (wv & 1) * 8;
        f32x4 acc[4][8];
#pragma unroll
        for (int m = 0; m < 4; ++m)
#pragma unroll
            for (int n = 0; n < 8; ++n) acc[m][n] = (f32x4)0.f;
        gemm48<8>(w1p + tile1 * 65536, ntbase, mtbase, hb, 512, l15, l4, lane, acc);
        __syncthreads();
        write48(acc, hb, mtbase, ntbase, b1, true, l15, l4);
    }
    __syncthreads();

    // ---------- layer 2: hbuf (ord2) -> hbuf (ord2); tile = group = idx2 -----
    {
        const int g0 = wv * 2;
        f32x4 acc[2][16];
#pragma unroll
        for (int g = 0; g < 2; ++g)
#pragma unroll
            for (int n = 0; n < 16; ++n) acc[g][n] = (f32x4)0.f;
#pragma unroll
        for (int kt = 0; kt < 8; ++kt) {
            bf16x8 a[2];
#pragma unroll
            for (int g = 0; g < 2; ++g) {
                int row = (g0 + g) * 16 + l15;
                a[g] = *(const bf16x8*)(hb + swz(row, kt * 64 + l4 * 16, 512));
            }
#pragma unroll
            for (int g = 0; g < 2; ++g) {
                const unsigned short* wp = w2p + (g0 + g) * 65536;
#pragma unroll
                for (int nt = 0; nt < 16; ++nt) {
                    bf16x8 b = *(const bf16x8*)(wp + ((kt * 16 + nt) * 64 + lane) * 8);
                    acc[g][nt] = __builtin_amdgcn_mfma_f32_16x16x32_bf16(a[g], b, acc[g][nt], 0, 0, 0);
                }
            }
        }
        __syncthreads();
#pragma unroll
        for (int g = 0; g < 2; ++g)
#pragma unroll
            for (int nt = 0; nt < 16; ++nt) {
                int col = nt * 16 + l15;
                float bv = b2[col];
#pragma unroll
                for (int r = 0; r < 4; ++r) {
                    float v = leaky(acc[g][nt][r] + bv);
                    int row = (g0 + g) * 16 + l4 * 4 + r;
                    *(unsigned short*)(hb + swz(row, col * 2, 512)) = f2bf(v);
                }
            }
    }
    __syncthreads();

    // ---------- head: [256][256] @ [256][3] + bl -> out ----------------------
    {
        int p = t >> 1, half = t & 1;
        float a0 = 0.f, a1 = 0.f, a2 = 0.f;
#pragma unroll
        for (int kk = 0; kk < 16; ++kk) {
            bf16x8 hv = *(const bf16x8*)(hb + swz(p, half * 256 + kk * 16, 512));
#pragma unroll
            for (int e = 0; e < 8; ++e) {
                float h = bf2f((unsigned short)hv[e]);
                int k = half * 128 + kk * 8 + e;
                a0 = fmaf(h, wl[k * 3 + 0], a0);
                a1 = fmaf(h, wl[k * 3 + 1], a1);
                a2 = fmaf(h, wl[k * 3 + 2], a2);
            }
        }
        a0 += __shfl_xor(a0, 1); a1 += __shfl_xor(a1, 1); a2 += __shfl_xor(a2, 1);
        if (half == 0) {
            int d2 = (p >> 7) & 1, d1 = (p >> 6) & 1, e2 = (p >> 5) & 1, e1 = (p >> 4) & 1;
            int d3 = (p >> 3) & 1, e3 = (p >> 2) & 1, d0 = (p >> 1) & 1, e0 = p & 1;
            int i = by * 16 + d3 * 8 + d2 * 4 + d1 * 2 + d0;
            int j = bx * 16 + e3 * 8 + e2 * 4 + e1 * 2 + e0;
            float* op = out + (i * 512 + j) * 3;
            op[0] = a0 + bl[0]; op[1] = a1 + bl[1]; op[2] = a2 + bl[2];
        }
    }
}

extern "C" void kernel_launch(void* const* d_in, const int* in_sizes, int n_in,
                              void* d_out, int out_size, void* d_ws, size_t ws_size,
                              hipStream_t stream) {
    // inputs: x, labels, w0, b0, w1, b1, w2, b2, w_last, b_last
    const float* w0 = (const float*)d_in[2];
    const float* b0 = (const float*)d_in[3];
    const float* w1 = (const float*)d_in[4];
    const float* b1 = (const float*)d_in[5];
    const float* w2 = (const float*)d_in[6];
    const float* b2 = (const float*)d_in[7];
    const float* wl = (const float*)d_in[8];
    const float* bl = (const float*)d_in[9];
    unsigned short* wpk = (unsigned short*)d_ws;     // needs 4.5 MiB of ws
    float* out = (float*)d_out;

    pack_w<<<1152, 256, 0, stream>>>(w0, w1, w2, wpk);
    dim3 grid(32, 32);
    loe_mfma<<<grid, 512, 0, stream>>>(wpk, b0, b1, b2, wl, bl, out);
}

// Round 3
// 318.518 us; speedup vs baseline: 4.1448x; 1.0155x over previous
//
#include <hip/hip_runtime.h>
#include <math.h>

// LoE tiled MLP — bf16 MFMA v3: transposed-output epilogue (D^T = mfma(w,h)),
// 1024-thread blocks (16 waves), MFMA head, rotate-swizzled LDS.
//
// Block = 16x16 px (256 px). Pixel bit naming: di = d3d2d1d0, dj = e3e2e1e0.
//   ord1 row s1 = [d3 e3 d2 d1 | e2 e1 d0 e0]  (L1 groups = s1>>6, Mtiles = s1>>4)
//   ord2 row s2 = [d2 d1 e2 e1 | d3 e3 d0 e0]  (L2 groups = Mtiles = idx2 = s2>>4)
// Weights pre-packed (pack_w) to bf16 A-role fragments [tile][kt][nt][lane][8];
// h is the B-role operand (lane&15 = pixel), so mfma(w_frag, h_frag) yields
// D^T: lane holds 4 CONSECUTIVE FEATURES (rows) of one pixel (col=lane&15)
// -> epilogue = 2 cvt_pk + 1 ds_write_b64 per fragment; row perms are free.
// Activation rows: 512B, phys = s*512 + ((off + (s&7)*64 + ((s>>3)&1)*32)&511)
// -> b64 writes conflict-free, b128 reads <=2-way.

typedef __attribute__((ext_vector_type(8))) short bf16x8;
typedef __attribute__((ext_vector_type(4))) float f32x4;

#define W0P 0
#define W1P 262144
#define W2P 1310720
#define WLP 2359296

__device__ __forceinline__ unsigned short f2bf(float f){
    unsigned b = __float_as_uint(f);
    return (unsigned short)((b + 0x7FFFu + ((b >> 16) & 1u)) >> 16);
}
__device__ __forceinline__ unsigned cvtpk(float lo, float hi){
    unsigned r;
    asm("v_cvt_pk_bf16_f32 %0, %1, %2" : "=v"(r) : "v"(lo), "v"(hi));
    return r;
}
__device__ __forceinline__ float leaky(float v){ return fmaxf(v, 0.2f * v); }
__device__ __forceinline__ int rowaddr(int s, int off){
    return s * 512 + ((off + (s & 7) * 64 + ((s >> 3) & 1) * 32) & 511);
}

// ---------------- weight pack: fp32 -> bf16 A-role fragment layout ----------
__global__ void pack_w(const float* __restrict__ w0, const float* __restrict__ w1,
                       const float* __restrict__ w2, const float* __restrict__ wl,
                       unsigned short* __restrict__ wp)
{
    int tid = blockIdx.x * 256 + threadIdx.x;
    if (tid < 32768) {                       // w0: [16][2][16][64][8], K padded 54->64
        int lane = tid & 63, kt = (tid >> 10) & 1, tile = tid >> 11;
        int n = ((tid >> 6) & 15) * 16 + (lane & 15);
        unsigned short* d = wp + W0P + tid * 8;
#pragma unroll
        for (int r = 0; r < 8; ++r) {
            int k = kt * 32 + (lane >> 4) * 8 + r;
            d[r] = (k < 54) ? f2bf(w0[(tile * 54 + k) * 256 + n]) : (unsigned short)0;
        }
    } else if (tid < 163840) {               // w1: [16][8][16][64][8]
        int idx = tid - 32768;
        int lane = idx & 63, kt = (idx >> 10) & 7, tile = idx >> 13;
        int n = ((idx >> 6) & 15) * 16 + (lane & 15);
        unsigned short* d = wp + W1P + idx * 8;
#pragma unroll
        for (int r = 0; r < 8; ++r)
            d[r] = f2bf(w1[(tile * 256 + kt * 32 + (lane >> 4) * 8 + r) * 256 + n]);
    } else if (tid < 294912) {               // w2: [16][8][16][64][8]
        int idx = tid - 163840;
        int lane = idx & 63, kt = (idx >> 10) & 7, tile = idx >> 13;
        int n = ((idx >> 6) & 15) * 16 + (lane & 15);
        unsigned short* d = wp + W2P + idx * 8;
#pragma unroll
        for (int r = 0; r < 8; ++r)
            d[r] = f2bf(w2[(tile * 256 + kt * 32 + (lane >> 4) * 8 + r) * 256 + n]);
    } else if (tid < 295424) {               // wl: [8][64][8], n<3 valid else 0
        int idx = tid - 294912;
        int lane = idx & 63, kt = idx >> 6;
        int n = lane & 15;
        unsigned short* d = wp + WLP + idx * 8;
#pragma unroll
        for (int r = 0; r < 8; ++r) {
            int k = kt * 32 + (lane >> 4) * 8 + r;
            d[r] = (n < 3) ? f2bf(wl[k * 3 + n]) : (unsigned short)0;
        }
    }
}

__global__ __launch_bounds__(1024, 4)
void loe_mfma(const unsigned short* __restrict__ wpk,
              const float* __restrict__ b0, const float* __restrict__ b1,
              const float* __restrict__ b2, const float* __restrict__ bl,
              float* __restrict__ out)
{
    __shared__ __align__(16) char hb[131072];

    const int t = threadIdx.x;
    const int w = t >> 6, lane = t & 63;
    const int l15 = lane & 15, l4 = lane >> 4;
    const int bx = blockIdx.x, by = blockIdx.y;   // 32 x 32 blocks of 16x16 px

    // ---------- posenc -> rows s1 (ord1), pitch 160B, features [0,54)+pad ----
    {
        int s = t >> 2, part = t & 3;
        int di = ((s >> 7) & 1) * 8 + ((s >> 5) & 1) * 4 + ((s >> 4) & 1) * 2 + ((s >> 1) & 1);
        int dj = ((s >> 6) & 1) * 8 + ((s >> 3) & 1) * 4 + ((s >> 2) & 1) * 2 + (s & 1);
        float xi = (float)(by * 16 + di) * (1.f / 256.f) - 1.f;
        float xj = (float)(bx * 16 + dj) * (1.f / 256.f) - 1.f;
        char* row = hb + s * 160;
        if (part == 3) {
            *(unsigned*)row = (unsigned)f2bf(xi) | ((unsigned)f2bf(xj) << 16);
#pragma unroll
            for (int b = 108; b < 128; b += 4) *(unsigned*)(row + b) = 0u;  // pad 54..63
        }
#pragma unroll
        for (int f = part; f < 13; f += 4) {
            float fr = 3.14159265358979323846f * (float)(1 << f);
            float si, ci, sj, cj;
            sincosf(xi * fr, &si, &ci);
            sincosf(xj * fr, &sj, &cj);
            *(unsigned*)(row + 4 + 8 * f) = (unsigned)f2bf(si) | ((unsigned)f2bf(ci) << 16);
            *(unsigned*)(row + 8 + 8 * f) = (unsigned)f2bf(sj) | ((unsigned)f2bf(cj) << 16);
        }
    }
    __syncthreads();

    // ---------- layer 0: posenc (ord1, K=64) -> main (ord1) ------------------
    {
        const int mg = w >> 2, ng = w & 3;
        const int tile0 = ((by >> 1) & 3) * 4 + ((bx >> 1) & 3);
        const unsigned short* wt = wpk + W0P + tile0 * 16384;
        f32x4 acc[4][4];
#pragma unroll
        for (int m = 0; m < 4; ++m)
#pragma unroll
            for (int n = 0; n < 4; ++n) acc[m][n] = (f32x4)0.f;
#pragma unroll
        for (int kt = 0; kt < 2; ++kt) {
            bf16x8 hf[4];
#pragma unroll
            for (int m = 0; m < 4; ++m) {
                int s = (mg * 4 + m) * 16 + l15;
                hf[m] = *(const bf16x8*)(hb + s * 160 + kt * 64 + l4 * 16);
            }
#pragma unroll
            for (int n = 0; n < 4; ++n) {
                bf16x8 wf = *(const bf16x8*)(wt + (kt * 16 + ng * 4 + n) * 512 + lane * 8);
#pragma unroll
                for (int m = 0; m < 4; ++m)
                    acc[m][n] = __builtin_amdgcn_mfma_f32_16x16x32_bf16(wf, hf[m], acc[m][n], 0, 0, 0);
            }
        }
        __syncthreads();
#pragma unroll
        for (int n = 0; n < 4; ++n) {
            int nt = ng * 4 + n;
            f32x4 bv = *(const f32x4*)(b0 + nt * 16 + l4 * 4);
#pragma unroll
            for (int m = 0; m < 4; ++m) {
                int s = (mg * 4 + m) * 16 + l15;
                uint2 pk;
                pk.x = cvtpk(leaky(acc[m][n][0] + bv[0]), leaky(acc[m][n][1] + bv[1]));
                pk.y = cvtpk(leaky(acc[m][n][2] + bv[2]), leaky(acc[m][n][3] + bv[3]));
                *(uint2*)(hb + rowaddr(s, nt * 32 + l4 * 8)) = pk;
            }
        }
    }
    __syncthreads();

    // ---------- layer 1: main (ord1) -> main (ord2) --------------------------
    {
        const int g = w >> 2, ng = w & 3;
        const int tile1 = ((2 * by + (g >> 1)) & 3) * 4 + ((2 * bx + (g & 1)) & 3);
        const unsigned short* wt = wpk + W1P + tile1 * 65536;
        f32x4 acc[4][4];
#pragma unroll
        for (int m = 0; m < 4; ++m)
#pragma unroll
            for (int n = 0; n < 4; ++n) acc[m][n] = (f32x4)0.f;
#pragma unroll
        for (int kt = 0; kt < 8; ++kt) {
            bf16x8 hf[4];
#pragma unroll
            for (int m = 0; m < 4; ++m) {
                int s = (g * 4 + m) * 16 + l15;
                hf[m] = *(const bf16x8*)(hb + rowaddr(s, kt * 64 + l4 * 16));
            }
#pragma unroll
            for (int n = 0; n < 4; ++n) {
                bf16x8 wf = *(const bf16x8*)(wt + (kt * 16 + ng * 4 + n) * 512 + lane * 8);
#pragma unroll
                for (int m = 0; m < 4; ++m)
                    acc[m][n] = __builtin_amdgcn_mfma_f32_16x16x32_bf16(wf, hf[m], acc[m][n], 0, 0, 0);
            }
        }
        __syncthreads();
#pragma unroll
        for (int n = 0; n < 4; ++n) {
            int nt = ng * 4 + n;
            f32x4 bv = *(const f32x4*)(b1 + nt * 16 + l4 * 4);
#pragma unroll
            for (int m = 0; m < 4; ++m) {
                int P1 = g * 4 + m;
                int s2 = ((((P1 & 3) << 2) | (l15 >> 2)) << 4) | ((P1 >> 2) << 2) | (l15 & 3);
                uint2 pk;
                pk.x = cvtpk(leaky(acc[m][n][0] + bv[0]), leaky(acc[m][n][1] + bv[1]));
                pk.y = cvtpk(leaky(acc[m][n][2] + bv[2]), leaky(acc[m][n][3] + bv[3]));
                *(uint2*)(hb + rowaddr(s2, nt * 32 + l4 * 8)) = pk;
            }
        }
    }
    __syncthreads();

    // ---------- layer 2: main (ord2) -> main (ord2); tile = group = wave -----
    {
        const unsigned short* wt = wpk + W2P + w * 65536;
        f32x4 acc[16];
#pragma unroll
        for (int n = 0; n < 16; ++n) acc[n] = (f32x4)0.f;
        const int s = w * 16 + l15;
#pragma unroll
        for (int kt = 0; kt < 8; ++kt) {
            bf16x8 hf = *(const bf16x8*)(hb + rowaddr(s, kt * 64 + l4 * 16));
#pragma unroll
            for (int n = 0; n < 16; ++n) {
                bf16x8 wf = *(const bf16x8*)(wt + (kt * 16 + n) * 512 + lane * 8);
                acc[n] = __builtin_amdgcn_mfma_f32_16x16x32_bf16(wf, hf, acc[n], 0, 0, 0);
            }
        }
        __syncthreads();
#pragma unroll
        for (int n = 0; n < 16; ++n) {
            f32x4 bv = *(const f32x4*)(b2 + n * 16 + l4 * 4);
            uint2 pk;
            pk.x = cvtpk(leaky(acc[n][0] + bv[0]), leaky(acc[n][1] + bv[1]));
            pk.y = cvtpk(leaky(acc[n][2] + bv[2]), leaky(acc[n][3] + bv[3]));
            *(uint2*)(hb + rowaddr(s, n * 32 + l4 * 8)) = pk;
        }
    }
    // no barrier: head wave w reads only rows w*16.. which wave w itself wrote

    // ---------- head: MFMA with packed w_last; stage; coalesced out ----------
    {
        f32x4 acc = (f32x4)0.f;
        const int s = w * 16 + l15;
#pragma unroll
        for (int kt = 0; kt < 8; ++kt) {
            bf16x8 hf = *(const bf16x8*)(hb + rowaddr(s, kt * 64 + l4 * 16));
            bf16x8 wf = *(const bf16x8*)(wpk + WLP + kt * 512 + lane * 8);
            acc = __builtin_amdgcn_mfma_f32_16x16x32_bf16(wf, hf, acc, 0, 0, 0);
        }
        __syncthreads();   // all head reads done before stage region overwrite
        if (l4 == 0) {
            int q = l15, P2 = w;
            int di = ((q >> 3) & 1) * 8 + ((P2 >> 3) & 1) * 4 + ((P2 >> 2) & 1) * 2 + ((q >> 1) & 1);
            int dj = ((q >> 2) & 1) * 8 + ((P2 >> 1) & 1) * 4 + (P2 & 1) * 2 + (q & 1);
            float* st = (float*)hb + (di * 16 + dj) * 3;
            st[0] = acc[0] + bl[0];
            st[1] = acc[1] + bl[1];
            st[2] = acc[2] + bl[2];
        }
    }
    __syncthreads();
    if (t < 768) {
        int row = t / 48, c = t - row * 48;
        out[(by * 16 + row) * 1536 + bx * 48 + c] = ((const float*)hb)[t];
    }
}

extern "C" void kernel_launch(void* const* d_in, const int* in_sizes, int n_in,
                              void* d_out, int out_size, void* d_ws, size_t ws_size,
                              hipStream_t stream) {
    // inputs: x, labels, w0, b0, w1, b1, w2, b2, w_last, b_last
    const float* w0 = (const float*)d_in[2];
    const float* b0 = (const float*)d_in[3];
    const float* w1 = (const float*)d_in[4];
    const float* b1 = (const float*)d_in[5];
    const float* w2 = (const float*)d_in[6];
    const float* b2 = (const float*)d_in[7];
    const float* wl = (const float*)d_in[8];
    const float* bl = (const float*)d_in[9];
    unsigned short* wpk = (unsigned short*)d_ws;     // ~4.73 MiB of ws
    float* out = (float*)d_out;

    pack_w<<<1154, 256, 0, stream>>>(w0, w1, w2, wl, wpk);
    dim3 grid(32, 32);
    loe_mfma<<<grid, 1024, 0, stream>>>(wpk, b0, b1, b2, bl, out);
}